// Round 1
// baseline (7309.909 us; speedup 1.0000x reference)
//
#include <hip/hip_runtime.h>
#include <math.h>

#define IN_C  512
#define HID   256
#define OUT_C 32
#define GAMMA 0.25f   // 1/(1+lam2), lam2=3
#define BETA  2.0f    // 1/(2*gamma)
#define LAM1  3.0f

// ---------------------------------------------------------------------------
// GEMM1: h1 = relu(x @ W1 + b1)   [M,512] x [512,256] -> [M,256], fp32 vector
// 128x128 tile, BK=16, 256 threads, 8x8 micro-tile per thread.
// ---------------------------------------------------------------------------
#define BM 128
#define BN 128
#define BK 16

__global__ __launch_bounds__(256) void gemm1_relu_kernel(
    const float* __restrict__ A, const float* __restrict__ B,
    const float* __restrict__ bias, float* __restrict__ C, int M)
{
    __shared__ float As[BK][BM + 4];   // +4 pad: breaks store-side bank aliasing
    __shared__ float Bs[BK][BN + 4];
    const int tid = threadIdx.x;
    const int bm = blockIdx.x * BM;
    const int bn = blockIdx.y * BN;
    const int tx = tid & 15;      // n-dir
    const int ty = tid >> 4;      // m-dir

    float acc[8][8];
#pragma unroll
    for (int i = 0; i < 8; ++i)
#pragma unroll
        for (int j = 0; j < 8; ++j) acc[i][j] = 0.f;

    const int a_row = tid >> 2;          // 0..63 (two passes -> 128 rows)
    const int a_col = (tid & 3) << 2;    // 0,4,8,12
    const int b_row = tid >> 5;          // 0..7  (two passes -> 16 rows)
    const int b_col = (tid & 31) << 2;   // 0..124

    for (int k0 = 0; k0 < IN_C; k0 += BK) {
#pragma unroll
        for (int r = 0; r < 2; ++r) {
            const int m = a_row + r * 64;
            const int gm = bm + m;
            float4 v = make_float4(0.f, 0.f, 0.f, 0.f);
            if (gm < M) v = *(const float4*)&A[(size_t)gm * IN_C + k0 + a_col];
            As[a_col + 0][m] = v.x;      // transpose on store: As[k][m]
            As[a_col + 1][m] = v.y;
            As[a_col + 2][m] = v.z;
            As[a_col + 3][m] = v.w;
        }
#pragma unroll
        for (int r = 0; r < 2; ++r) {
            const int kk = b_row + r * 8;
            *(float4*)&Bs[kk][b_col] =
                *(const float4*)&B[(size_t)(k0 + kk) * HID + bn + b_col];
        }
        __syncthreads();
#pragma unroll
        for (int kk = 0; kk < BK; ++kk) {
            float a[8], b[8];
            *(float4*)&a[0] = *(float4*)&As[kk][ty * 8];
            *(float4*)&a[4] = *(float4*)&As[kk][ty * 8 + 4];
            *(float4*)&b[0] = *(float4*)&Bs[kk][tx * 8];
            *(float4*)&b[4] = *(float4*)&Bs[kk][tx * 8 + 4];
#pragma unroll
            for (int i = 0; i < 8; ++i)
#pragma unroll
                for (int j = 0; j < 8; ++j)
                    acc[i][j] = fmaf(a[i], b[j], acc[i][j]);
        }
        __syncthreads();
    }

#pragma unroll
    for (int i = 0; i < 8; ++i) {
        const int gm = bm + ty * 8 + i;
        if (gm >= M) continue;
#pragma unroll
        for (int j = 0; j < 8; j += 4) {
            const int gn = bn + tx * 8 + j;
            float4 v;
            v.x = fmaxf(acc[i][j + 0] + bias[gn + 0], 0.f);
            v.y = fmaxf(acc[i][j + 1] + bias[gn + 1], 0.f);
            v.z = fmaxf(acc[i][j + 2] + bias[gn + 2], 0.f);
            v.w = fmaxf(acc[i][j + 3] + bias[gn + 3], 0.f);
            *(float4*)&C[(size_t)gm * HID + gn] = v;
        }
    }
}

// ---------------------------------------------------------------------------
// GEMM2: h = h1 @ W2 + b2; also y0 = gamma*h.  [M,256] x [256,32] -> [M,32]
// Block = 128 rows; thread = 4 rows x 4 channels; all-b128 LDS reads.
// ---------------------------------------------------------------------------
#define G2_ROWS 128
#define G2_KT   64

__global__ __launch_bounds__(256) void gemm2_kernel(
    const float* __restrict__ H1, const float* __restrict__ W2,
    const float* __restrict__ b2, float* __restrict__ H,
    float* __restrict__ Y, int M)
{
    __shared__ float W2s[HID * OUT_C];             // 32 KB, whole W2
    __shared__ float rows_s[G2_ROWS][G2_KT + 4];   // 34.8 KB, k-chunk of rows
    const int tid = threadIdx.x;
    const int brow = blockIdx.x * G2_ROWS;
    const int cg = tid & 7;        // channel group: channels cg*4..cg*4+3
    const int rg = tid >> 3;       // row group: rows rg*4..rg*4+3 (0..31)

    // stage all of W2 once (2048 float4 / 256 threads = 8 each)
#pragma unroll
    for (int r = 0; r < 8; ++r)
        ((float4*)W2s)[tid + r * 256] = ((const float4*)W2)[tid + r * 256];

    float acc[4][4];
#pragma unroll
    for (int r = 0; r < 4; ++r)
#pragma unroll
        for (int c = 0; c < 4; ++c) acc[r][c] = 0.f;

    for (int k0 = 0; k0 < HID; k0 += G2_KT) {
        __syncthreads();
        // stage 128 rows x 64 k of h1: 2048 float4 / 256 threads = 8 each
#pragma unroll
        for (int i = 0; i < 8; ++i) {
            const int idx = tid + i * 256;
            const int rl = idx >> 4;          // 0..127
            const int c4 = idx & 15;          // float4 index within chunk
            const int gr = brow + rl;
            float4 v = make_float4(0.f, 0.f, 0.f, 0.f);
            if (gr < M) v = *(const float4*)&H1[(size_t)gr * HID + k0 + c4 * 4];
            *(float4*)&rows_s[rl][c4 * 4] = v;
        }
        __syncthreads();
#pragma unroll
        for (int kq = 0; kq < G2_KT / 4; ++kq) {
            float4 w[4];
#pragma unroll
            for (int j = 0; j < 4; ++j)
                w[j] = ((const float4*)W2s)[(k0 + kq * 4 + j) * 8 + cg];
#pragma unroll
            for (int r = 0; r < 4; ++r) {
                const float4 rh = *(const float4*)&rows_s[rg * 4 + r][kq * 4];
                acc[r][0] = fmaf(rh.x, w[0].x, acc[r][0]);
                acc[r][1] = fmaf(rh.x, w[0].y, acc[r][1]);
                acc[r][2] = fmaf(rh.x, w[0].z, acc[r][2]);
                acc[r][3] = fmaf(rh.x, w[0].w, acc[r][3]);
                acc[r][0] = fmaf(rh.y, w[1].x, acc[r][0]);
                acc[r][1] = fmaf(rh.y, w[1].y, acc[r][1]);
                acc[r][2] = fmaf(rh.y, w[1].z, acc[r][2]);
                acc[r][3] = fmaf(rh.y, w[1].w, acc[r][3]);
                acc[r][0] = fmaf(rh.z, w[2].x, acc[r][0]);
                acc[r][1] = fmaf(rh.z, w[2].y, acc[r][1]);
                acc[r][2] = fmaf(rh.z, w[2].z, acc[r][2]);
                acc[r][3] = fmaf(rh.z, w[2].w, acc[r][3]);
                acc[r][0] = fmaf(rh.w, w[3].x, acc[r][0]);
                acc[r][1] = fmaf(rh.w, w[3].y, acc[r][1]);
                acc[r][2] = fmaf(rh.w, w[3].z, acc[r][2]);
                acc[r][3] = fmaf(rh.w, w[3].w, acc[r][3]);
            }
        }
    }

    const float4 bias = *(const float4*)&b2[cg * 4];
#pragma unroll
    for (int r = 0; r < 4; ++r) {
        const int grow = brow + rg * 4 + r;
        if (grow >= M) continue;
        float4 s;
        s.x = acc[r][0] + bias.x;
        s.y = acc[r][1] + bias.y;
        s.z = acc[r][2] + bias.z;
        s.w = acc[r][3] + bias.w;
        *(float4*)&H[(size_t)grow * OUT_C + cg * 4] = s;
        float4 y0;
        y0.x = GAMMA * s.x; y0.y = GAMMA * s.y;
        y0.z = GAMMA * s.z; y0.w = GAMMA * s.w;
        *(float4*)&Y[(size_t)grow * OUT_C + cg * 4] = y0;
    }
}

// ---------------------------------------------------------------------------
// degree + inverse-sqrt
// ---------------------------------------------------------------------------
__global__ void deg_kernel(const int* __restrict__ ei, float* __restrict__ deg, int n)
{
    const int t = blockIdx.x * blockDim.x + threadIdx.x;
    if (t < n) atomicAdd(&deg[ei[t]], 1.f);
}

__global__ void dis_kernel(const float* __restrict__ deg, float* __restrict__ dis, int n)
{
    const int t = blockIdx.x * blockDim.x + threadIdx.x;
    if (t < n) dis[t] = 1.f / sqrtf(fmaxf(deg[t], 1.f));
}

// ---------------------------------------------------------------------------
// EMP edge step: z update + scatter of Delta^T z (atomics into ATZ).
// 8 threads per edge, float4 per thread (32 channels).
// FIRST: z_in == 0 (skip read).  LAST: z not needed again (skip write).
// ---------------------------------------------------------------------------
template <bool FIRST, bool LAST>
__global__ __launch_bounds__(256) void edge_kernel(
    const int* __restrict__ row, const int* __restrict__ col,
    const float* __restrict__ dis, const float* __restrict__ Y,
    float* __restrict__ Z, float* __restrict__ ATZ, int E)
{
    const int t = blockIdx.x * 256 + threadIdx.x;
    const int e = t >> 3;
    if (e >= E) return;
    const int c = (t & 7) << 2;
    const int r = row[e], cl = col[e];
    const float dr = dis[r], dc = dis[cl];
    const float4 yr = *(const float4*)&Y[(size_t)r * OUT_C + c];
    const float4 yc = *(const float4*)&Y[(size_t)cl * OUT_C + c];
    float4 z;
    if (FIRST) z = make_float4(0.f, 0.f, 0.f, 0.f);
    else       z = *(const float4*)&Z[(size_t)e * OUT_C + c];
    z.x = fminf(fmaxf(z.x + BETA * (yr.x * dr - yc.x * dc), -LAM1), LAM1);
    z.y = fminf(fmaxf(z.y + BETA * (yr.y * dr - yc.y * dc), -LAM1), LAM1);
    z.z = fminf(fmaxf(z.z + BETA * (yr.z * dr - yc.z * dc), -LAM1), LAM1);
    z.w = fminf(fmaxf(z.w + BETA * (yr.w * dr - yc.w * dc), -LAM1), LAM1);
    if (!LAST) *(float4*)&Z[(size_t)e * OUT_C + c] = z;
    float* ar = &ATZ[(size_t)r * OUT_C + c];
    atomicAdd(ar + 0, z.x * dr);
    atomicAdd(ar + 1, z.y * dr);
    atomicAdd(ar + 2, z.z * dr);
    atomicAdd(ar + 3, z.w * dr);
    float* ac = &ATZ[(size_t)cl * OUT_C + c];
    atomicAdd(ac + 0, -z.x * dc);
    atomicAdd(ac + 1, -z.y * dc);
    atomicAdd(ac + 2, -z.z * dc);
    atomicAdd(ac + 3, -z.w * dc);
}

// ---------------------------------------------------------------------------
// y = gamma*(h - atz); reset atz for the next iteration.
// ---------------------------------------------------------------------------
__global__ void y_update_kernel(const float* __restrict__ H, float* __restrict__ ATZ,
                                float* __restrict__ Y, int n4)
{
    const int t = blockIdx.x * blockDim.x + threadIdx.x;
    if (t >= n4) return;
    const float4 h = ((const float4*)H)[t];
    const float4 a = ((const float4*)ATZ)[t];
    float4 y;
    y.x = GAMMA * (h.x - a.x);
    y.y = GAMMA * (h.y - a.y);
    y.z = GAMMA * (h.z - a.z);
    y.w = GAMMA * (h.w - a.w);
    ((float4*)Y)[t] = y;
    ((float4*)ATZ)[t] = make_float4(0.f, 0.f, 0.f, 0.f);
}

// ---------------------------------------------------------------------------
// final y update fused with row-wise log_softmax (32 channels = 32 lanes).
// ---------------------------------------------------------------------------
__global__ __launch_bounds__(256) void y_final_kernel(
    const float* __restrict__ H, const float* __restrict__ ATZ,
    float* __restrict__ OUT, int M)
{
    const int t = blockIdx.x * 256 + threadIdx.x;
    const int r = t >> 5;
    if (r >= M) return;
    const float v = GAMMA * (H[t] - ATZ[t]);
    float m = v;
#pragma unroll
    for (int off = 16; off; off >>= 1) m = fmaxf(m, __shfl_xor(m, off, 32));
    const float ex = expf(v - m);
    float s = ex;
#pragma unroll
    for (int off = 16; off; off >>= 1) s += __shfl_xor(s, off, 32);
    OUT[t] = v - m - logf(s);
}

// ---------------------------------------------------------------------------
extern "C" void kernel_launch(void* const* d_in, const int* in_sizes, int n_in,
                              void* d_out, int out_size, void* d_ws, size_t ws_size,
                              hipStream_t stream)
{
    const float* x  = (const float*)d_in[0];
    const int*   ei = (const int*)d_in[1];   // [2,E] int32
    const float* W1 = (const float*)d_in[2];
    const float* b1 = (const float*)d_in[3];
    const float* W2 = (const float*)d_in[4];
    const float* b2 = (const float*)d_in[5];
    const int M = in_sizes[0] / IN_C;        // 100000
    const int E = in_sizes[1] / 2;           // 1600000
    const int* row = ei;
    const int* col = ei + E;

    // workspace layout (fp32): h1 | h | y | atz | deg | dis | z  (~347 MB)
    float* ws  = (float*)d_ws;
    float* h1  = ws;
    float* h   = h1  + (size_t)M * HID;
    float* y   = h   + (size_t)M * OUT_C;
    float* atz = y   + (size_t)M * OUT_C;
    float* deg = atz + (size_t)M * OUT_C;
    float* dis = deg + M;
    float* z   = dis + M;                    // E*32 floats

    hipMemsetAsync(deg, 0, (size_t)M * sizeof(float), stream);
    hipMemsetAsync(atz, 0, (size_t)M * OUT_C * sizeof(float), stream);

    dim3 g1((M + BM - 1) / BM, HID / BN);
    gemm1_relu_kernel<<<g1, 256, 0, stream>>>(x, W1, b1, h1, M);
    gemm2_kernel<<<(M + G2_ROWS - 1) / G2_ROWS, 256, 0, stream>>>(h1, W2, b2, h, y, M);
    deg_kernel<<<(2 * E + 255) / 256, 256, 0, stream>>>(ei, deg, 2 * E);
    dis_kernel<<<(M + 255) / 256, 256, 0, stream>>>(deg, dis, M);

    const int eblocks = (E * 8 + 255) / 256;
    const int n4 = M * OUT_C / 4;
    const int yblocks = (n4 + 255) / 256;

    // K = 5 proximal iterations
    edge_kernel<true, false><<<eblocks, 256, 0, stream>>>(row, col, dis, y, z, atz, E);
    y_update_kernel<<<yblocks, 256, 0, stream>>>(h, atz, y, n4);
    for (int it = 1; it <= 3; ++it) {
        edge_kernel<false, false><<<eblocks, 256, 0, stream>>>(row, col, dis, y, z, atz, E);
        y_update_kernel<<<yblocks, 256, 0, stream>>>(h, atz, y, n4);
    }
    edge_kernel<false, true><<<eblocks, 256, 0, stream>>>(row, col, dis, y, z, atz, E);
    y_final_kernel<<<((M * OUT_C) + 255) / 256, 256, 0, stream>>>(h, atz, (float*)d_out, M);
}

// Round 2
// 1918.404 us; speedup vs baseline: 3.8104x; 3.8104x over previous
//
#include <hip/hip_runtime.h>
#include <math.h>

#define IN_C  512
#define HID   256
#define OUT_C 32
#define GAMMA 0.25f   // 1/(1+lam2), lam2=3
#define BETA  2.0f    // 1/(2*gamma)
#define LAM1  3.0f

// ---------------------------------------------------------------------------
// GEMM1: h1 = relu(x @ W1 + b1)   [M,512] x [512,256] -> [M,256], fp32 vector
// ---------------------------------------------------------------------------
#define BM 128
#define BN 128
#define BK 16

__global__ __launch_bounds__(256) void gemm1_relu_kernel(
    const float* __restrict__ A, const float* __restrict__ B,
    const float* __restrict__ bias, float* __restrict__ C, int M)
{
    __shared__ float As[BK][BM + 4];
    __shared__ float Bs[BK][BN + 4];
    const int tid = threadIdx.x;
    const int bm = blockIdx.x * BM;
    const int bn = blockIdx.y * BN;
    const int tx = tid & 15;
    const int ty = tid >> 4;

    float acc[8][8];
#pragma unroll
    for (int i = 0; i < 8; ++i)
#pragma unroll
        for (int j = 0; j < 8; ++j) acc[i][j] = 0.f;

    const int a_row = tid >> 2;
    const int a_col = (tid & 3) << 2;
    const int b_row = tid >> 5;
    const int b_col = (tid & 31) << 2;

    for (int k0 = 0; k0 < IN_C; k0 += BK) {
#pragma unroll
        for (int r = 0; r < 2; ++r) {
            const int m = a_row + r * 64;
            const int gm = bm + m;
            float4 v = make_float4(0.f, 0.f, 0.f, 0.f);
            if (gm < M) v = *(const float4*)&A[(size_t)gm * IN_C + k0 + a_col];
            As[a_col + 0][m] = v.x;
            As[a_col + 1][m] = v.y;
            As[a_col + 2][m] = v.z;
            As[a_col + 3][m] = v.w;
        }
#pragma unroll
        for (int r = 0; r < 2; ++r) {
            const int kk = b_row + r * 8;
            *(float4*)&Bs[kk][b_col] =
                *(const float4*)&B[(size_t)(k0 + kk) * HID + bn + b_col];
        }
        __syncthreads();
#pragma unroll
        for (int kk = 0; kk < BK; ++kk) {
            float a[8], b[8];
            *(float4*)&a[0] = *(float4*)&As[kk][ty * 8];
            *(float4*)&a[4] = *(float4*)&As[kk][ty * 8 + 4];
            *(float4*)&b[0] = *(float4*)&Bs[kk][tx * 8];
            *(float4*)&b[4] = *(float4*)&Bs[kk][tx * 8 + 4];
#pragma unroll
            for (int i = 0; i < 8; ++i)
#pragma unroll
                for (int j = 0; j < 8; ++j)
                    acc[i][j] = fmaf(a[i], b[j], acc[i][j]);
        }
        __syncthreads();
    }

#pragma unroll
    for (int i = 0; i < 8; ++i) {
        const int gm = bm + ty * 8 + i;
        if (gm >= M) continue;
#pragma unroll
        for (int j = 0; j < 8; j += 4) {
            const int gn = bn + tx * 8 + j;
            float4 v;
            v.x = fmaxf(acc[i][j + 0] + bias[gn + 0], 0.f);
            v.y = fmaxf(acc[i][j + 1] + bias[gn + 1], 0.f);
            v.z = fmaxf(acc[i][j + 2] + bias[gn + 2], 0.f);
            v.w = fmaxf(acc[i][j + 3] + bias[gn + 3], 0.f);
            *(float4*)&C[(size_t)gm * HID + gn] = v;
        }
    }
}

// ---------------------------------------------------------------------------
// GEMM2: h = h1 @ W2 + b2; also y0 = gamma*h.  [M,256] x [256,32] -> [M,32]
// ---------------------------------------------------------------------------
#define G2_ROWS 128
#define G2_KT   64

__global__ __launch_bounds__(256) void gemm2_kernel(
    const float* __restrict__ H1, const float* __restrict__ W2,
    const float* __restrict__ b2, float* __restrict__ H,
    float* __restrict__ Y, int M)
{
    __shared__ float W2s[HID * OUT_C];
    __shared__ float rows_s[G2_ROWS][G2_KT + 4];
    const int tid = threadIdx.x;
    const int brow = blockIdx.x * G2_ROWS;
    const int cg = tid & 7;
    const int rg = tid >> 3;

#pragma unroll
    for (int r = 0; r < 8; ++r)
        ((float4*)W2s)[tid + r * 256] = ((const float4*)W2)[tid + r * 256];

    float acc[4][4];
#pragma unroll
    for (int r = 0; r < 4; ++r)
#pragma unroll
        for (int c = 0; c < 4; ++c) acc[r][c] = 0.f;

    for (int k0 = 0; k0 < HID; k0 += G2_KT) {
        __syncthreads();
#pragma unroll
        for (int i = 0; i < 8; ++i) {
            const int idx = tid + i * 256;
            const int rl = idx >> 4;
            const int c4 = idx & 15;
            const int gr = brow + rl;
            float4 v = make_float4(0.f, 0.f, 0.f, 0.f);
            if (gr < M) v = *(const float4*)&H1[(size_t)gr * HID + k0 + c4 * 4];
            *(float4*)&rows_s[rl][c4 * 4] = v;
        }
        __syncthreads();
#pragma unroll
        for (int kq = 0; kq < G2_KT / 4; ++kq) {
            float4 w[4];
#pragma unroll
            for (int j = 0; j < 4; ++j)
                w[j] = ((const float4*)W2s)[(k0 + kq * 4 + j) * 8 + cg];
#pragma unroll
            for (int r = 0; r < 4; ++r) {
                const float4 rh = *(const float4*)&rows_s[rg * 4 + r][kq * 4];
                acc[r][0] = fmaf(rh.x, w[0].x, acc[r][0]);
                acc[r][1] = fmaf(rh.x, w[0].y, acc[r][1]);
                acc[r][2] = fmaf(rh.x, w[0].z, acc[r][2]);
                acc[r][3] = fmaf(rh.x, w[0].w, acc[r][3]);
                acc[r][0] = fmaf(rh.y, w[1].x, acc[r][0]);
                acc[r][1] = fmaf(rh.y, w[1].y, acc[r][1]);
                acc[r][2] = fmaf(rh.y, w[1].z, acc[r][2]);
                acc[r][3] = fmaf(rh.y, w[1].w, acc[r][3]);
                acc[r][0] = fmaf(rh.z, w[2].x, acc[r][0]);
                acc[r][1] = fmaf(rh.z, w[2].y, acc[r][1]);
                acc[r][2] = fmaf(rh.z, w[2].z, acc[r][2]);
                acc[r][3] = fmaf(rh.z, w[2].w, acc[r][3]);
                acc[r][0] = fmaf(rh.w, w[3].x, acc[r][0]);
                acc[r][1] = fmaf(rh.w, w[3].y, acc[r][1]);
                acc[r][2] = fmaf(rh.w, w[3].z, acc[r][2]);
                acc[r][3] = fmaf(rh.w, w[3].w, acc[r][3]);
            }
        }
    }

    const float4 bias = *(const float4*)&b2[cg * 4];
#pragma unroll
    for (int r = 0; r < 4; ++r) {
        const int grow = brow + rg * 4 + r;
        if (grow >= M) continue;
        float4 s;
        s.x = acc[r][0] + bias.x;
        s.y = acc[r][1] + bias.y;
        s.z = acc[r][2] + bias.z;
        s.w = acc[r][3] + bias.w;
        *(float4*)&H[(size_t)grow * OUT_C + cg * 4] = s;
        float4 y0;
        y0.x = GAMMA * s.x; y0.y = GAMMA * s.y;
        y0.z = GAMMA * s.z; y0.w = GAMMA * s.w;
        *(float4*)&Y[(size_t)grow * OUT_C + cg * 4] = y0;
    }
}

// ---------------------------------------------------------------------------
// CSR preprocessing: histogram -> 3-phase exclusive scan (+dis) -> scatter
// entries[pos] = edge_id | (side<<31); side 1 = appears as col (negative).
// ---------------------------------------------------------------------------
__global__ void hist_kernel(const int* __restrict__ ei, int* __restrict__ counts, int n)
{
    const int t = blockIdx.x * blockDim.x + threadIdx.x;
    if (t < n) atomicAdd(&counts[ei[t]], 1);
}

#define SCAN_CHUNK 1024

__global__ __launch_bounds__(256) void scan1_kernel(
    const int* __restrict__ counts, int* __restrict__ bsum, int N)
{
    __shared__ int sm[256];
    const int tid = threadIdx.x;
    const int base = blockIdx.x * SCAN_CHUNK + tid * 4;
    int s = 0;
#pragma unroll
    for (int i = 0; i < 4; ++i)
        if (base + i < N) s += counts[base + i];
    sm[tid] = s;
    __syncthreads();
    for (int off = 128; off; off >>= 1) {
        if (tid < off) sm[tid] += sm[tid + off];
        __syncthreads();
    }
    if (tid == 0) bsum[blockIdx.x] = sm[0];
}

__global__ void scan2_kernel(int* __restrict__ bsum, int* __restrict__ boff, int nb)
{
    if (threadIdx.x == 0 && blockIdx.x == 0) {
        int acc = 0;
        for (int i = 0; i < nb; ++i) { boff[i] = acc; acc += bsum[i]; }
    }
}

__global__ __launch_bounds__(256) void scan3_kernel(
    const int* __restrict__ counts, const int* __restrict__ boff,
    int* __restrict__ rowptr, int* __restrict__ cursor,
    float* __restrict__ dis, int N)
{
    __shared__ int sm[256];
    const int tid = threadIdx.x;
    const int base = blockIdx.x * SCAN_CHUNK + tid * 4;
    int c[4];
#pragma unroll
    for (int i = 0; i < 4; ++i)
        c[i] = (base + i < N) ? counts[base + i] : 0;
    const int tsum = c[0] + c[1] + c[2] + c[3];
    sm[tid] = tsum;
    __syncthreads();
    // Hillis-Steele inclusive scan over 256 thread-sums
    for (int off = 1; off < 256; off <<= 1) {
        int v = (tid >= off) ? sm[tid - off] : 0;
        __syncthreads();
        sm[tid] += v;
        __syncthreads();
    }
    int run = boff[blockIdx.x] + sm[tid] - tsum;  // exclusive
#pragma unroll
    for (int i = 0; i < 4; ++i) {
        if (base + i < N) {
            rowptr[base + i] = run;
            cursor[base + i] = run;
            dis[base + i] = 1.f / sqrtf(fmaxf((float)c[i], 1.f));
        }
        run += c[i];
    }
}

__global__ void scatter_kernel(const int* __restrict__ ei, int* __restrict__ cursor,
                               int* __restrict__ entries, int E2, int E)
{
    const int t = blockIdx.x * blockDim.x + threadIdx.x;
    if (t >= E2) return;
    const int node = ei[t];
    const int pos = atomicAdd(&cursor[node], 1);
    entries[pos] = (t < E) ? t : ((t - E) | 0x80000000);
}

// ---------------------------------------------------------------------------
// EMP edge step: z = clip(z + beta*(y[row]*dr - y[col]*dc)).  No atomics.
// 8 threads per edge, float4 per thread (32 channels).
// ---------------------------------------------------------------------------
template <bool FIRST>
__global__ __launch_bounds__(256) void edge_kernel(
    const int* __restrict__ row, const int* __restrict__ col,
    const float* __restrict__ dis, const float* __restrict__ Y,
    float* __restrict__ Z, int E)
{
    const int t = blockIdx.x * 256 + threadIdx.x;
    const int e = t >> 3;
    if (e >= E) return;
    const int c = (t & 7) << 2;
    const int r = row[e], cl = col[e];
    const float dr = dis[r], dc = dis[cl];
    const float4 yr = *(const float4*)&Y[(size_t)r * OUT_C + c];
    const float4 yc = *(const float4*)&Y[(size_t)cl * OUT_C + c];
    float4 z;
    if (FIRST) z = make_float4(0.f, 0.f, 0.f, 0.f);
    else       z = *(const float4*)&Z[(size_t)e * OUT_C + c];
    z.x = fminf(fmaxf(z.x + BETA * (yr.x * dr - yc.x * dc), -LAM1), LAM1);
    z.y = fminf(fmaxf(z.y + BETA * (yr.y * dr - yc.y * dc), -LAM1), LAM1);
    z.z = fminf(fmaxf(z.z + BETA * (yr.z * dr - yc.z * dc), -LAM1), LAM1);
    z.w = fminf(fmaxf(z.w + BETA * (yr.w * dr - yc.w * dc), -LAM1), LAM1);
    *(float4*)&Z[(size_t)e * OUT_C + c] = z;
}

// ---------------------------------------------------------------------------
// Node step: atz[n] = dis[n] * sum_{incident e} (+/-) z[e]; y = gamma*(h-atz).
// 8 threads per node (4 channels each); LAST fuses log_softmax -> OUT.
// ---------------------------------------------------------------------------
template <bool LAST>
__global__ __launch_bounds__(256) void node_kernel(
    const int* __restrict__ rowptr, const int* __restrict__ counts,
    const int* __restrict__ entries, const float* __restrict__ Z,
    const float* __restrict__ dis, const float* __restrict__ H,
    float* __restrict__ Y, float* __restrict__ OUT, int N)
{
    const int t = blockIdx.x * 256 + threadIdx.x;
    const int n = t >> 3;
    if (n >= N) return;
    const int c = (t & 7) << 2;
    const int base = rowptr[n];
    const int d = counts[n];

    float4 s = make_float4(0.f, 0.f, 0.f, 0.f);
    int j = 0;
    for (; j + 1 < d; j += 2) {   // 2-way unroll for memory parallelism
        const int e0 = entries[base + j];
        const int e1 = entries[base + j + 1];
        const float4 z0 = *(const float4*)&Z[(size_t)(e0 & 0x7fffffff) * OUT_C + c];
        const float4 z1 = *(const float4*)&Z[(size_t)(e1 & 0x7fffffff) * OUT_C + c];
        const float s0 = (e0 < 0) ? -1.f : 1.f;
        const float s1 = (e1 < 0) ? -1.f : 1.f;
        s.x = fmaf(s0, z0.x, s.x); s.y = fmaf(s0, z0.y, s.y);
        s.z = fmaf(s0, z0.z, s.z); s.w = fmaf(s0, z0.w, s.w);
        s.x = fmaf(s1, z1.x, s.x); s.y = fmaf(s1, z1.y, s.y);
        s.z = fmaf(s1, z1.z, s.z); s.w = fmaf(s1, z1.w, s.w);
    }
    if (j < d) {
        const int e0 = entries[base + j];
        const float4 z0 = *(const float4*)&Z[(size_t)(e0 & 0x7fffffff) * OUT_C + c];
        const float s0 = (e0 < 0) ? -1.f : 1.f;
        s.x = fmaf(s0, z0.x, s.x); s.y = fmaf(s0, z0.y, s.y);
        s.z = fmaf(s0, z0.z, s.z); s.w = fmaf(s0, z0.w, s.w);
    }
    const float dn = dis[n];
    const float4 h = *(const float4*)&H[(size_t)n * OUT_C + c];
    float4 v;
    v.x = GAMMA * (h.x - dn * s.x);
    v.y = GAMMA * (h.y - dn * s.y);
    v.z = GAMMA * (h.z - dn * s.z);
    v.w = GAMMA * (h.w - dn * s.w);

    if (!LAST) {
        *(float4*)&Y[(size_t)n * OUT_C + c] = v;
    } else {
        // log_softmax across the 8-lane group (consecutive lanes)
        float m = fmaxf(fmaxf(v.x, v.y), fmaxf(v.z, v.w));
#pragma unroll
        for (int off = 4; off; off >>= 1) m = fmaxf(m, __shfl_xor(m, off, 8));
        float sum = expf(v.x - m) + expf(v.y - m) + expf(v.z - m) + expf(v.w - m);
#pragma unroll
        for (int off = 4; off; off >>= 1) sum += __shfl_xor(sum, off, 8);
        const float lse = m + logf(sum);
        float4 o;
        o.x = v.x - lse; o.y = v.y - lse; o.z = v.z - lse; o.w = v.w - lse;
        *(float4*)&OUT[(size_t)n * OUT_C + c] = o;
    }
}

// ---------------------------------------------------------------------------
extern "C" void kernel_launch(void* const* d_in, const int* in_sizes, int n_in,
                              void* d_out, int out_size, void* d_ws, size_t ws_size,
                              hipStream_t stream)
{
    const float* x  = (const float*)d_in[0];
    const int*   ei = (const int*)d_in[1];   // [2,E] int32
    const float* W1 = (const float*)d_in[2];
    const float* b1 = (const float*)d_in[3];
    const float* W2 = (const float*)d_in[4];
    const float* b2 = (const float*)d_in[5];
    const int M = in_sizes[0] / IN_C;        // 100000
    const int E = in_sizes[1] / 2;           // 1600000
    const int E2 = 2 * E;
    const int* row = ei;
    const int* col = ei + E;

    // workspace layout (bytes):
    //   z (E*32 f32, h1 aliased at its start — h1 dead before z first written)
    //   h | y | counts | rowptr | cursor | dis | bsum/boff | entries
    float* ws = (float*)d_ws;
    float* z  = ws;                          // E*32 floats (204.8 MB)
    float* h1 = ws;                          // alias: M*HID floats (102.4 MB)
    float* h  = z + (size_t)E * OUT_C;
    float* y  = h + (size_t)M * OUT_C;
    int* counts  = (int*)(y + (size_t)M * OUT_C);
    int* rowptr  = counts + M;
    int* cursor  = rowptr + M;
    float* dis   = (float*)(cursor + M);
    const int nb = (M + SCAN_CHUNK - 1) / SCAN_CHUNK;
    int* bsum    = (int*)(dis + M);
    int* boff    = bsum + nb;
    int* entries = boff + nb;                // E2 ints (12.8 MB)

    hipMemsetAsync(counts, 0, (size_t)M * sizeof(int), stream);

    // MLP
    dim3 g1((M + BM - 1) / BM, HID / BN);
    gemm1_relu_kernel<<<g1, 256, 0, stream>>>(x, W1, b1, h1, M);
    gemm2_kernel<<<(M + G2_ROWS - 1) / G2_ROWS, 256, 0, stream>>>(h1, W2, b2, h, y, M);

    // CSR build (h1 no longer needed; z region free to overwrite after this)
    hist_kernel<<<(E2 + 255) / 256, 256, 0, stream>>>(ei, counts, E2);
    scan1_kernel<<<nb, 256, 0, stream>>>(counts, bsum, M);
    scan2_kernel<<<1, 64, 0, stream>>>(bsum, boff, nb);
    scan3_kernel<<<nb, 256, 0, stream>>>(counts, boff, rowptr, cursor, dis, M);
    scatter_kernel<<<(E2 + 255) / 256, 256, 0, stream>>>(ei, cursor, entries, E2, E);

    const int eblocks = (E * 8 + 255) / 256;
    const int nblocks = (M * 8 + 255) / 256;

    // K = 5 proximal iterations: edge (z update) then node (atz gather + y)
    edge_kernel<true><<<eblocks, 256, 0, stream>>>(row, col, dis, y, z, E);
    node_kernel<false><<<nblocks, 256, 0, stream>>>(rowptr, counts, entries, z, dis, h, y, nullptr, M);
    for (int it = 1; it < 4; ++it) {
        edge_kernel<false><<<eblocks, 256, 0, stream>>>(row, col, dis, y, z, E);
        node_kernel<false><<<nblocks, 256, 0, stream>>>(rowptr, counts, entries, z, dis, h, y, nullptr, M);
    }
    edge_kernel<false><<<eblocks, 256, 0, stream>>>(row, col, dis, y, z, E);
    node_kernel<true><<<nblocks, 256, 0, stream>>>(rowptr, counts, entries, z, dis, h, y, (float*)d_out, M);
}

// Round 4
// 1705.326 us; speedup vs baseline: 4.2865x; 1.1249x over previous
//
#include <hip/hip_runtime.h>
#include <math.h>

#define IN_C  512
#define HID   256
#define OUT_C 32
#define GAMMA 0.25f   // 1/(1+lam2), lam2=3
#define BETA  2.0f    // 1/(2*gamma)
#define LAM1  3.0f
#define ZS    10922.0f        // int16 scale: 3*ZS = 32766 <= 32767
#define ZSI   (1.0f / 10922.0f)

// ---------------------------------------------------------------------------
// GEMM1: h1 = relu(x @ W1 + b1)   [M,512] x [512,256] -> [M,256], fp32 vector
// B-fragment split (tx*4 and 64+tx*4) keeps LDS reads at free 2-way aliasing.
// ---------------------------------------------------------------------------
#define BM 128
#define BN 128
#define BK 16

__global__ __launch_bounds__(256) void gemm1_relu_kernel(
    const float* __restrict__ A, const float* __restrict__ B,
    const float* __restrict__ bias, float* __restrict__ C, int M)
{
    __shared__ float As[BK][BM + 4];
    __shared__ float Bs[BK][BN + 4];
    const int tid = threadIdx.x;
    const int bm = blockIdx.x * BM;
    const int bn = blockIdx.y * BN;
    const int tx = tid & 15;
    const int ty = tid >> 4;

    float acc[8][8];
#pragma unroll
    for (int i = 0; i < 8; ++i)
#pragma unroll
        for (int j = 0; j < 8; ++j) acc[i][j] = 0.f;

    const int a_row = tid >> 2;
    const int a_col = (tid & 3) << 2;
    const int b_row = tid >> 5;
    const int b_col = (tid & 31) << 2;

    for (int k0 = 0; k0 < IN_C; k0 += BK) {
#pragma unroll
        for (int r = 0; r < 2; ++r) {
            const int m = a_row + r * 64;
            const int gm = bm + m;
            float4 v = make_float4(0.f, 0.f, 0.f, 0.f);
            if (gm < M) v = *(const float4*)&A[(size_t)gm * IN_C + k0 + a_col];
            As[a_col + 0][m] = v.x;
            As[a_col + 1][m] = v.y;
            As[a_col + 2][m] = v.z;
            As[a_col + 3][m] = v.w;
        }
#pragma unroll
        for (int r = 0; r < 2; ++r) {
            const int kk = b_row + r * 8;
            *(float4*)&Bs[kk][b_col] =
                *(const float4*)&B[(size_t)(k0 + kk) * HID + bn + b_col];
        }
        __syncthreads();
#pragma unroll
        for (int kk = 0; kk < BK; ++kk) {
            float a[8], b[8];
            *(float4*)&a[0] = *(float4*)&As[kk][ty * 8];
            *(float4*)&a[4] = *(float4*)&As[kk][ty * 8 + 4];
            *(float4*)&b[0] = *(float4*)&Bs[kk][tx * 4];        // banks 2-way
            *(float4*)&b[4] = *(float4*)&Bs[kk][64 + tx * 4];   // banks 2-way
#pragma unroll
            for (int i = 0; i < 8; ++i)
#pragma unroll
                for (int j = 0; j < 8; ++j)
                    acc[i][j] = fmaf(a[i], b[j], acc[i][j]);
        }
        __syncthreads();
    }

#pragma unroll
    for (int i = 0; i < 8; ++i) {
        const int gm = bm + ty * 8 + i;
        if (gm >= M) continue;
#pragma unroll
        for (int g = 0; g < 2; ++g) {
            const int gn = bn + g * 64 + tx * 4;
            float4 v;
            v.x = fmaxf(acc[i][g * 4 + 0] + bias[gn + 0], 0.f);
            v.y = fmaxf(acc[i][g * 4 + 1] + bias[gn + 1], 0.f);
            v.z = fmaxf(acc[i][g * 4 + 2] + bias[gn + 2], 0.f);
            v.w = fmaxf(acc[i][g * 4 + 3] + bias[gn + 3], 0.f);
            *(float4*)&C[(size_t)gm * HID + gn] = v;
        }
    }
}

// ---------------------------------------------------------------------------
// GEMM2: h = h1 @ W2 + b2; also y0 = gamma*h.  [M,256] x [256,32] -> [M,32]
// ---------------------------------------------------------------------------
#define G2_ROWS 128
#define G2_KT   64

__global__ __launch_bounds__(256) void gemm2_kernel(
    const float* __restrict__ H1, const float* __restrict__ W2,
    const float* __restrict__ b2, float* __restrict__ H,
    float* __restrict__ Y, int M)
{
    __shared__ float W2s[HID * OUT_C];
    __shared__ float rows_s[G2_ROWS][G2_KT + 4];
    const int tid = threadIdx.x;
    const int brow = blockIdx.x * G2_ROWS;
    const int cg = tid & 7;
    const int rg = tid >> 3;

#pragma unroll
    for (int r = 0; r < 8; ++r)
        ((float4*)W2s)[tid + r * 256] = ((const float4*)W2)[tid + r * 256];

    float acc[4][4];
#pragma unroll
    for (int r = 0; r < 4; ++r)
#pragma unroll
        for (int c = 0; c < 4; ++c) acc[r][c] = 0.f;

    for (int k0 = 0; k0 < HID; k0 += G2_KT) {
        __syncthreads();
#pragma unroll
        for (int i = 0; i < 8; ++i) {
            const int idx = tid + i * 256;
            const int rl = idx >> 4;
            const int c4 = idx & 15;
            const int gr = brow + rl;
            float4 v = make_float4(0.f, 0.f, 0.f, 0.f);
            if (gr < M) v = *(const float4*)&H1[(size_t)gr * HID + k0 + c4 * 4];
            *(float4*)&rows_s[rl][c4 * 4] = v;
        }
        __syncthreads();
#pragma unroll
        for (int kq = 0; kq < G2_KT / 4; ++kq) {
            float4 w[4];
#pragma unroll
            for (int j = 0; j < 4; ++j)
                w[j] = ((const float4*)W2s)[(k0 + kq * 4 + j) * 8 + cg];
#pragma unroll
            for (int r = 0; r < 4; ++r) {
                const float4 rh = *(const float4*)&rows_s[rg * 4 + r][kq * 4];
                acc[r][0] = fmaf(rh.x, w[0].x, acc[r][0]);
                acc[r][1] = fmaf(rh.x, w[0].y, acc[r][1]);
                acc[r][2] = fmaf(rh.x, w[0].z, acc[r][2]);
                acc[r][3] = fmaf(rh.x, w[0].w, acc[r][3]);
                acc[r][0] = fmaf(rh.y, w[1].x, acc[r][0]);
                acc[r][1] = fmaf(rh.y, w[1].y, acc[r][1]);
                acc[r][2] = fmaf(rh.y, w[1].z, acc[r][2]);
                acc[r][3] = fmaf(rh.y, w[1].w, acc[r][3]);
                acc[r][0] = fmaf(rh.z, w[2].x, acc[r][0]);
                acc[r][1] = fmaf(rh.z, w[2].y, acc[r][1]);
                acc[r][2] = fmaf(rh.z, w[2].z, acc[r][2]);
                acc[r][3] = fmaf(rh.z, w[2].w, acc[r][3]);
                acc[r][0] = fmaf(rh.w, w[3].x, acc[r][0]);
                acc[r][1] = fmaf(rh.w, w[3].y, acc[r][1]);
                acc[r][2] = fmaf(rh.w, w[3].z, acc[r][2]);
                acc[r][3] = fmaf(rh.w, w[3].w, acc[r][3]);
            }
        }
    }

    const float4 bias = *(const float4*)&b2[cg * 4];
#pragma unroll
    for (int r = 0; r < 4; ++r) {
        const int grow = brow + rg * 4 + r;
        if (grow >= M) continue;
        float4 s;
        s.x = acc[r][0] + bias.x;
        s.y = acc[r][1] + bias.y;
        s.z = acc[r][2] + bias.z;
        s.w = acc[r][3] + bias.w;
        *(float4*)&H[(size_t)grow * OUT_C + cg * 4] = s;
        float4 y0;
        y0.x = GAMMA * s.x; y0.y = GAMMA * s.y;
        y0.z = GAMMA * s.z; y0.w = GAMMA * s.w;
        *(float4*)&Y[(size_t)grow * OUT_C + cg * 4] = y0;
    }
}

// ---------------------------------------------------------------------------
// Preprocess: per-side histograms -> scans -> scatter.
// Edges are renumbered sorted-by-row: new id = position in row-CSR, so the
// row-side incidences of node n are the contiguous ids [rowptr[n], +cnt_r[n]).
// col-side incidence list stores (new_edge_id, other_node) pairs.
// ---------------------------------------------------------------------------
__global__ void hist2_kernel(const int* __restrict__ row, const int* __restrict__ col,
                             int* __restrict__ cnt_r, int* __restrict__ cnt_c, int E)
{
    const int t = blockIdx.x * blockDim.x + threadIdx.x;
    if (t >= E) return;
    atomicAdd(&cnt_r[row[t]], 1);
    atomicAdd(&cnt_c[col[t]], 1);
}

__global__ void dis_kernel(const int* __restrict__ cnt_r, const int* __restrict__ cnt_c,
                           float* __restrict__ dis, int N)
{
    const int t = blockIdx.x * blockDim.x + threadIdx.x;
    if (t < N) dis[t] = 1.f / sqrtf(fmaxf((float)(cnt_r[t] + cnt_c[t]), 1.f));
}

#define SCAN_CHUNK 1024

__global__ __launch_bounds__(256) void scan1_kernel(
    const int* __restrict__ counts, int* __restrict__ bsum, int N)
{
    __shared__ int sm[256];
    const int tid = threadIdx.x;
    const int base = blockIdx.x * SCAN_CHUNK + tid * 4;
    int s = 0;
#pragma unroll
    for (int i = 0; i < 4; ++i)
        if (base + i < N) s += counts[base + i];
    sm[tid] = s;
    __syncthreads();
    for (int off = 128; off; off >>= 1) {
        if (tid < off) sm[tid] += sm[tid + off];
        __syncthreads();
    }
    if (tid == 0) bsum[blockIdx.x] = sm[0];
}

__global__ void scan2_kernel(int* __restrict__ bsum, int* __restrict__ boff, int nb)
{
    if (threadIdx.x == 0 && blockIdx.x == 0) {
        int acc = 0;
        for (int i = 0; i < nb; ++i) { boff[i] = acc; acc += bsum[i]; }
    }
}

__global__ __launch_bounds__(256) void scan3_kernel(
    const int* __restrict__ counts, const int* __restrict__ boff,
    int* __restrict__ ptr, int* __restrict__ cursor, int N)
{
    __shared__ int sm[256];
    const int tid = threadIdx.x;
    const int base = blockIdx.x * SCAN_CHUNK + tid * 4;
    int c[4];
#pragma unroll
    for (int i = 0; i < 4; ++i)
        c[i] = (base + i < N) ? counts[base + i] : 0;
    const int tsum = c[0] + c[1] + c[2] + c[3];
    sm[tid] = tsum;
    __syncthreads();
    for (int off = 1; off < 256; off <<= 1) {
        int v = (tid >= off) ? sm[tid - off] : 0;
        __syncthreads();
        sm[tid] += v;
        __syncthreads();
    }
    int run = boff[blockIdx.x] + sm[tid] - tsum;  // exclusive
#pragma unroll
    for (int i = 0; i < 4; ++i) {
        if (base + i < N) {
            ptr[base + i] = run;
            cursor[base + i] = run;
        }
        run += c[i];
    }
}

__global__ void scatter2_kernel(const int* __restrict__ row, const int* __restrict__ col,
                                int* __restrict__ cur_r, int* __restrict__ cur_c,
                                int* __restrict__ col_s, int2* __restrict__ entries_c, int E)
{
    const int t = blockIdx.x * blockDim.x + threadIdx.x;
    if (t >= E) return;
    const int r = row[t], c = col[t];
    const int nid = atomicAdd(&cur_r[r], 1);    // new edge id (row-sorted)
    col_s[nid] = c;
    const int pc = atomicAdd(&cur_c[c], 1);
    entries_c[pc] = make_int2(nid, r);
}

// ---------------------------------------------------------------------------
// Fused EMP iteration: z-update + node aggregation + y-update.
// z int16 (scale ZS), double-buffered; y double-buffered. 8 threads/node.
// Row-side (contiguous ids) owns the z store; col side recomputes identically.
// ---------------------------------------------------------------------------
__device__ __forceinline__ float clip1(float v)
{
    return fminf(fmaxf(v, -LAM1), LAM1);
}

__device__ __forceinline__ float4 zload4(const short* p)
{
    const short4 s = *(const short4*)p;
    return make_float4(s.x * ZSI, s.y * ZSI, s.z * ZSI, s.w * ZSI);
}

__device__ __forceinline__ void zstore4(short* p, float4 z)
{
    short4 s;
    s.x = (short)__float2int_rn(z.x * ZS);
    s.y = (short)__float2int_rn(z.y * ZS);
    s.z = (short)__float2int_rn(z.z * ZS);
    s.w = (short)__float2int_rn(z.w * ZS);
    *(short4*)p = s;
}

template <bool FIRST, bool LAST>
__global__ __launch_bounds__(256) void emp_kernel(
    const int* __restrict__ rowptr, const int* __restrict__ cnt_r,
    const int* __restrict__ col_s,
    const int* __restrict__ colptr, const int* __restrict__ cnt_c,
    const int2* __restrict__ entries_c,
    const short* __restrict__ zin, short* __restrict__ zout,
    const float* __restrict__ dis, const float* __restrict__ H,
    const float* __restrict__ Yold, float* __restrict__ Ynew,
    float* __restrict__ OUT, int N)
{
    const int t = blockIdx.x * 256 + threadIdx.x;
    const int n = t >> 3;
    if (n >= N) return;
    const int c4 = (t & 7) << 2;
    const float dn = dis[n];
    const float4 ys = *(const float4*)&Yold[(size_t)n * OUT_C + c4];
    const float4 ysdn = make_float4(ys.x * dn, ys.y * dn, ys.z * dn, ys.w * dn);

    float4 acc = make_float4(0.f, 0.f, 0.f, 0.f);

    // ---- row side: edges [rowptr[n], rowptr[n]+cnt_r[n]), contiguous ids
    {
        const int b = rowptr[n];
        const int d = cnt_r[n];
        for (int i = 0; i < d; ++i) {
            const int e = b + i;
            const int other = col_s[e];
            const float dt = dis[other];
            const float4 yo = *(const float4*)&Yold[(size_t)other * OUT_C + c4];
            float4 z;
            if (FIRST) z = make_float4(0.f, 0.f, 0.f, 0.f);
            else       z = zload4(&zin[(size_t)e * OUT_C + c4]);
            z.x = clip1(z.x + BETA * (ysdn.x - yo.x * dt));
            z.y = clip1(z.y + BETA * (ysdn.y - yo.y * dt));
            z.z = clip1(z.z + BETA * (ysdn.z - yo.z * dt));
            z.w = clip1(z.w + BETA * (ysdn.w - yo.w * dt));
            acc.x += z.x; acc.y += z.y; acc.z += z.z; acc.w += z.w;
            if (!LAST) zstore4(&zout[(size_t)e * OUT_C + c4], z);
        }
    }

    // ---- col side: entry list (edge id random, no store)
    {
        const int b = colptr[n];
        const int d = cnt_c[n];
        for (int i = 0; i < d; ++i) {
            const int2 en = entries_c[b + i];
            const float dt = dis[en.y];
            const float4 yo = *(const float4*)&Yold[(size_t)en.y * OUT_C + c4];
            float4 z;
            if (FIRST) z = make_float4(0.f, 0.f, 0.f, 0.f);
            else       z = zload4(&zin[(size_t)en.x * OUT_C + c4]);
            z.x = clip1(z.x + BETA * (yo.x * dt - ysdn.x));
            z.y = clip1(z.y + BETA * (yo.y * dt - ysdn.y));
            z.z = clip1(z.z + BETA * (yo.z * dt - ysdn.z));
            z.w = clip1(z.w + BETA * (yo.w * dt - ysdn.w));
            acc.x -= z.x; acc.y -= z.y; acc.z -= z.z; acc.w -= z.w;
        }
    }

    const float4 h4 = *(const float4*)&H[(size_t)n * OUT_C + c4];
    float4 v;
    v.x = GAMMA * (h4.x - dn * acc.x);
    v.y = GAMMA * (h4.y - dn * acc.y);
    v.z = GAMMA * (h4.z - dn * acc.z);
    v.w = GAMMA * (h4.w - dn * acc.w);

    if (!LAST) {
        *(float4*)&Ynew[(size_t)n * OUT_C + c4] = v;
    } else {
        float m = fmaxf(fmaxf(v.x, v.y), fmaxf(v.z, v.w));
#pragma unroll
        for (int off = 4; off; off >>= 1) m = fmaxf(m, __shfl_xor(m, off, 8));
        float sum = expf(v.x - m) + expf(v.y - m) + expf(v.z - m) + expf(v.w - m);
#pragma unroll
        for (int off = 4; off; off >>= 1) sum += __shfl_xor(sum, off, 8);
        const float lse = m + logf(sum);
        float4 o;
        o.x = v.x - lse; o.y = v.y - lse; o.z = v.z - lse; o.w = v.w - lse;
        *(float4*)&OUT[(size_t)n * OUT_C + c4] = o;
    }
}

// ---------------------------------------------------------------------------
extern "C" void kernel_launch(void* const* d_in, const int* in_sizes, int n_in,
                              void* d_out, int out_size, void* d_ws, size_t ws_size,
                              hipStream_t stream)
{
    const float* x  = (const float*)d_in[0];
    const int*   ei = (const int*)d_in[1];   // [2,E] int32
    const float* W1 = (const float*)d_in[2];
    const float* b1 = (const float*)d_in[3];
    const float* W2 = (const float*)d_in[4];
    const float* b2 = (const float*)d_in[5];
    const int M = in_sizes[0] / IN_C;        // 100000
    const int E = in_sizes[1] / 2;           // 1600000
    const int* row = ei;
    const int* col = ei + E;

    // workspace layout:
    //   zA, zB: int16 [E,32] (102.4 MB each); h1 (fp32, 102.4 MB) aliases zA
    //   (h1 dead after gemm2; zA first written by emp iter 0 which is later)
    char* ws = (char*)d_ws;
    short* zA = (short*)ws;
    short* zB = zA + (size_t)E * OUT_C;
    float* h1 = (float*)ws;                               // alias over zA
    float* h  = (float*)(zB + (size_t)E * OUT_C);
    float* y0 = h  + (size_t)M * OUT_C;
    float* y1 = y0 + (size_t)M * OUT_C;
    int* cnt_r   = (int*)(y1 + (size_t)M * OUT_C);
    int* cnt_c   = cnt_r + M;
    int* rowptr  = cnt_c + M;
    int* colptr  = rowptr + M;
    int* cur_r   = colptr + M;
    int* cur_c   = cur_r + M;
    float* dis   = (float*)(cur_c + M);
    const int nb = (M + SCAN_CHUNK - 1) / SCAN_CHUNK;
    int* bsum    = (int*)(dis + M);
    int* boff    = bsum + nb;
    int* col_s   = boff + nb;                             // E ints
    int2* entries_c = (int2*)(col_s + E);                 // E int2

    hipMemsetAsync(cnt_r, 0, 2 * (size_t)M * sizeof(int), stream);

    // MLP
    dim3 g1((M + BM - 1) / BM, HID / BN);
    gemm1_relu_kernel<<<g1, 256, 0, stream>>>(x, W1, b1, h1, M);
    gemm2_kernel<<<(M + G2_ROWS - 1) / G2_ROWS, 256, 0, stream>>>(h1, W2, b2, h, y0, M);

    // CSR build + edge renumbering
    hist2_kernel<<<(E + 255) / 256, 256, 0, stream>>>(row, col, cnt_r, cnt_c, E);
    dis_kernel<<<(M + 255) / 256, 256, 0, stream>>>(cnt_r, cnt_c, dis, M);
    scan1_kernel<<<nb, 256, 0, stream>>>(cnt_r, bsum, M);
    scan2_kernel<<<1, 64, 0, stream>>>(bsum, boff, nb);
    scan3_kernel<<<nb, 256, 0, stream>>>(cnt_r, boff, rowptr, cur_r, M);
    scan1_kernel<<<nb, 256, 0, stream>>>(cnt_c, bsum, M);
    scan2_kernel<<<1, 64, 0, stream>>>(bsum, boff, nb);
    scan3_kernel<<<nb, 256, 0, stream>>>(cnt_c, boff, colptr, cur_c, M);
    scatter2_kernel<<<(E + 255) / 256, 256, 0, stream>>>(row, col, cur_r, cur_c,
                                                         col_s, entries_c, E);

    // K = 5 fused EMP iterations (z: -, A, B, A, B; y: 0->1->0->1->0->OUT)
    const int nblocks = (M * 8 + 255) / 256;
    emp_kernel<true, false><<<nblocks, 256, 0, stream>>>(
        rowptr, cnt_r, col_s, colptr, cnt_c, entries_c,
        (const short*)nullptr, zA, dis, h, y0, y1, nullptr, M);
    emp_kernel<false, false><<<nblocks, 256, 0, stream>>>(
        rowptr, cnt_r, col_s, colptr, cnt_c, entries_c,
        zA, zB, dis, h, y1, y0, nullptr, M);
    emp_kernel<false, false><<<nblocks, 256, 0, stream>>>(
        rowptr, cnt_r, col_s, colptr, cnt_c, entries_c,
        zB, zA, dis, h, y0, y1, nullptr, M);
    emp_kernel<false, false><<<nblocks, 256, 0, stream>>>(
        rowptr, cnt_r, col_s, colptr, cnt_c, entries_c,
        zA, zB, dis, h, y1, y0, nullptr, M);
    emp_kernel<false, true><<<nblocks, 256, 0, stream>>>(
        rowptr, cnt_r, col_s, colptr, cnt_c, entries_c,
        zB, nullptr, dis, h, y0, nullptr, (float*)d_out, M);
}